// Round 1
// baseline (209.592 us; speedup 1.0000x reference)
//
#include <hip/hip_runtime.h>

#define ALPHA 0.2f
constexpr int B_   = 64;
constexpr int N_   = 2048;
constexpr int IN_  = 1024;
constexpr int OUT_ = 1024;
constexpr int NCHUNK = 8;   // n-split for the g = att^T * f pass

// ---- workspace layout (float offsets) ----
constexpr size_t WA1   = 0;                                  // 1024  : W^T a1
constexpr size_t WA2   = 1024;                               // 1024  : W^T a2
constexpr size_t C12   = 2048;                               // 2     : w_b.a1, w_b.a2
constexpr size_t E0    = 2112;                               // 64    : f[b,0,:].wa1
constexpr size_t SATT  = 4096;                               // B*N   : s, then att in-place
constexpr size_t GPART = SATT + (size_t)B_ * N_;             // B*NCHUNK*IN
constexpr size_t GV    = GPART + (size_t)B_ * NCHUNK * IN_;  // B*IN
// total floats = GV + B_*IN_ = 724992  (~2.9 MB)

__device__ inline float wave_reduce_sum(float v) {
    #pragma unroll
    for (int off = 32; off > 0; off >>= 1) v += __shfl_xor(v, off);
    return v;
}

// wa1[i] = sum_d W[d,i]*a1[d], wa2[i] = sum_d W[d,i]*a2[d]
__global__ void kA(const float* __restrict__ W, const float* __restrict__ aw,
                   float* __restrict__ ws) {
    int t   = threadIdx.x;
    int col = blockIdx.x * 64 + (t & 63);
    int dg  = t >> 6;  // 4 d-groups of 256 rows
    const float* a1 = aw;
    const float* a2 = aw + OUT_;
    float acc1 = 0.f, acc2 = 0.f;
    for (int d = dg * 256; d < dg * 256 + 256; ++d) {
        float w = W[(size_t)d * IN_ + col];
        acc1 += w * a1[d];
        acc2 += w * a2[d];
    }
    __shared__ float r1[4][64], r2[4][64];
    r1[dg][t & 63] = acc1;
    r2[dg][t & 63] = acc2;
    __syncthreads();
    if (t < 64) {
        float s1 = r1[0][t] + r1[1][t] + r1[2][t] + r1[3][t];
        float s2 = r2[0][t] + r2[1][t] + r2[2][t] + r2[3][t];
        ws[WA1 + blockIdx.x * 64 + t] = s1;
        ws[WA2 + blockIdx.x * 64 + t] = s2;
    }
}

// c1 = w_b.a1, c2 = w_b.a2
__global__ void kG(const float* __restrict__ wb, const float* __restrict__ aw,
                   float* __restrict__ ws) {
    int t = threadIdx.x;
    float p1 = 0.f, p2 = 0.f;
    for (int d = t; d < OUT_; d += 256) {
        p1 += wb[d] * aw[d];
        p2 += wb[d] * aw[OUT_ + d];
    }
    __shared__ float r1[256], r2[256];
    r1[t] = p1; r2[t] = p2;
    __syncthreads();
    for (int off = 128; off > 0; off >>= 1) {
        if (t < off) { r1[t] += r1[t + off]; r2[t] += r2[t + off]; }
        __syncthreads();
    }
    if (t == 0) { ws[C12] = r1[0]; ws[C12 + 1] = r2[0]; }
}

// s[b,n] = f[b,n,:].wa2 ; e0[b] = f[b,0,:].wa1   (one wave per row)
__global__ void kB(const float* __restrict__ f, float* __restrict__ ws) {
    __shared__ float swa2[IN_];
    int t = threadIdx.x;
    ((float4*)swa2)[t] = ((const float4*)(ws + WA2))[t];
    __syncthreads();
    int wave = t >> 6, lane = t & 63;
    int row  = blockIdx.x * 4 + wave;          // row = b*N + n
    const float4* f4 = (const float4*)(f + (size_t)row * IN_);
    float acc = 0.f;
    #pragma unroll
    for (int k = 0; k < 4; ++k) {
        float4 v = f4[k * 64 + lane];
        int i = (k * 64 + lane) * 4;
        acc += v.x * swa2[i] + v.y * swa2[i + 1] + v.z * swa2[i + 2] + v.w * swa2[i + 3];
    }
    acc = wave_reduce_sum(acc);
    if (lane == 0) ws[SATT + row] = acc;
    if ((row & (N_ - 1)) == 0) {               // n == 0 rows: also dot with wa1
        const float4* wa1_4 = (const float4*)(ws + WA1);
        float a = 0.f;
        #pragma unroll
        for (int k = 0; k < 4; ++k) {
            float4 v  = f4[k * 64 + lane];
            float4 w1 = wa1_4[k * 64 + lane];
            a += v.x * w1.x + v.y * w1.y + v.z * w1.z + v.w * w1.w;
        }
        a = wave_reduce_sum(a);
        if (lane == 0) ws[E0 + (row >> 11)] = a;
    }
}

// att[b,:] = softmax_n( leaky(e0[b]+c1+c2+a_b + s[b,n]) )  (in-place over s)
__global__ void kC(float* __restrict__ ws, const float* __restrict__ ab) {
    int b = blockIdx.x, t = threadIdx.x;
    __shared__ float vals[N_];
    __shared__ float red[256];
    float cst = ws[E0 + b] + ws[C12] + ws[C12 + 1] + ab[0];
    float* srow = ws + SATT + (size_t)b * N_;
    float lmax = -1e30f;
    for (int n = t; n < N_; n += 256) {
        float v = srow[n] + cst;
        v = v >= 0.f ? v : ALPHA * v;
        vals[n] = v;
        lmax = fmaxf(lmax, v);
    }
    red[t] = lmax;
    __syncthreads();
    for (int off = 128; off > 0; off >>= 1) {
        if (t < off) red[t] = fmaxf(red[t], red[t + off]);
        __syncthreads();
    }
    float mx = red[0];
    __syncthreads();
    float lsum = 0.f;
    for (int n = t; n < N_; n += 256) {
        float e = __expf(vals[n] - mx);
        vals[n] = e;
        lsum += e;
    }
    red[t] = lsum;
    __syncthreads();
    for (int off = 128; off > 0; off >>= 1) {
        if (t < off) red[t] += red[t + off];
        __syncthreads();
    }
    float inv = 1.0f / red[0];
    for (int n = t; n < N_; n += 256) srow[n] = vals[n] * inv;
}

// gpart[b,chunk,i] = sum_{n in chunk} att[b,n] * f[b,n,i]
__global__ void kD(const float* __restrict__ f, float* __restrict__ ws) {
    int b = blockIdx.y, chunk = blockIdx.x, t = threadIdx.x;
    __shared__ float satt[256];
    satt[t] = ws[SATT + (size_t)b * N_ + chunk * 256 + t];
    __syncthreads();
    const float4* f4 = (const float4*)(f + ((size_t)b * N_ + (size_t)chunk * 256) * IN_);
    float4 acc = make_float4(0.f, 0.f, 0.f, 0.f);
    #pragma unroll 4
    for (int n = 0; n < 256; ++n) {
        float a  = satt[n];
        float4 v = f4[(size_t)n * 256 + t];
        acc.x += a * v.x; acc.y += a * v.y; acc.z += a * v.z; acc.w += a * v.w;
    }
    ((float4*)(ws + GPART))[((size_t)b * NCHUNK + chunk) * 256 + t] = acc;
}

// g[b,i] = sum_chunk gpart[b,chunk,i]
__global__ void kE(float* __restrict__ ws) {
    int b = blockIdx.x, t = threadIdx.x;
    const float4* gp = (const float4*)(ws + GPART);
    float4 acc = make_float4(0.f, 0.f, 0.f, 0.f);
    #pragma unroll
    for (int c = 0; c < NCHUNK; ++c) {
        float4 v = gp[((size_t)b * NCHUNK + c) * 256 + t];
        acc.x += v.x; acc.y += v.y; acc.z += v.z; acc.w += v.w;
    }
    ((float4*)(ws + GV))[b * 256 + t] = acc;
}

// out[b,d] = relu( g[b,:].W[d,:] + w_b[d] + bias_out[d] )   (one wave per (b,d))
__global__ void kF(const float* __restrict__ W, const float* __restrict__ wb,
                   const float* __restrict__ bias, const float* __restrict__ ws,
                   float* __restrict__ out) {
    int b = blockIdx.x, t = threadIdx.x;
    int dbase = blockIdx.y * 4;
    __shared__ float sg[IN_];
    ((float4*)sg)[t] = ((const float4*)(ws + GV))[b * 256 + t];
    __syncthreads();
    int wave = t >> 6, lane = t & 63;
    int d = dbase + wave;
    const float4* w4 = (const float4*)(W + (size_t)d * IN_);
    float acc = 0.f;
    #pragma unroll
    for (int k = 0; k < 4; ++k) {
        float4 wv = w4[k * 64 + lane];
        int i = (k * 64 + lane) * 4;
        acc += wv.x * sg[i] + wv.y * sg[i + 1] + wv.z * sg[i + 2] + wv.w * sg[i + 3];
    }
    acc = wave_reduce_sum(acc);
    if (lane == 0) {
        float p = acc + wb[d] + bias[d];
        out[(size_t)b * OUT_ + d] = p > 0.f ? p : 0.f;
    }
}

extern "C" void kernel_launch(void* const* d_in, const int* in_sizes, int n_in,
                              void* d_out, int out_size, void* d_ws, size_t ws_size,
                              hipStream_t stream) {
    const float* f    = (const float*)d_in[0];  // (64,2048,1024)
    const float* W    = (const float*)d_in[1];  // (1024,1024)
    const float* wb   = (const float*)d_in[2];  // (1024,)
    const float* aw   = (const float*)d_in[3];  // (2048,)
    const float* ab   = (const float*)d_in[4];  // scalar
    const float* bias = (const float*)d_in[5];  // (1024,)
    float* out = (float*)d_out;                 // (64,1,1024) f32
    float* ws  = (float*)d_ws;

    kA<<<dim3(IN_ / 64), 256, 0, stream>>>(W, aw, ws);
    kG<<<dim3(1), 256, 0, stream>>>(wb, aw, ws);
    kB<<<dim3((B_ * N_) / 4), 256, 0, stream>>>(f, ws);
    kC<<<dim3(B_), 256, 0, stream>>>(ws, ab);
    kD<<<dim3(NCHUNK, B_), 256, 0, stream>>>(f, ws);
    kE<<<dim3(B_), 256, 0, stream>>>(ws);
    kF<<<dim3(B_, OUT_ / 4), 256, 0, stream>>>(W, wb, bias, ws, out);
}

// Round 2
// 134.996 us; speedup vs baseline: 1.5526x; 1.5526x over previous
//
#include <hip/hip_runtime.h>

#define ALPHA 0.2f
constexpr int B_   = 64;
constexpr int N_   = 2048;
constexpr int IN_  = 1024;
constexpr int OUT_ = 1024;
constexpr int CHUNK = 256;            // rows per workgroup in main pass
constexpr int NCH   = N_ / CHUNK;     // 8 chunks per batch
constexpr int RPW   = CHUNK / 4;      // 64 rows per wave (4 waves/block)

// ---- workspace layout (float offsets), total 593920 floats (~2.4 MB) ----
constexpr size_t WA1   = 0;                                   // 1024 : W^T a1
constexpr size_t WA2   = 1024;                                // 1024 : W^T a2
constexpr size_t C12   = 2048;                                // 2    : w_b.a1, w_b.a2
constexpr size_t E0    = 2112;                                // 64   : f[b,0,:].wa1
constexpr size_t ZPART = 2176;                                // B*NCH = 512
constexpr size_t GPART = 4096;                                // B*NCH*IN = 524288
constexpr size_t GV    = GPART + (size_t)B_ * NCH * IN_;      // B*IN = 65536

__device__ inline float wave_reduce_sum(float v) {
    #pragma unroll
    for (int off = 32; off > 0; off >>= 1) v += __shfl_xor(v, off);
    return v;
}

// wa1[i] = sum_d W[d,i]*a1[d], wa2[i] = sum_d W[d,i]*a2[d]
__global__ void kA(const float* __restrict__ W, const float* __restrict__ aw,
                   float* __restrict__ ws) {
    int t   = threadIdx.x;
    int col = blockIdx.x * 64 + (t & 63);
    int dg  = t >> 6;
    const float* a1 = aw;
    const float* a2 = aw + OUT_;
    float acc1 = 0.f, acc2 = 0.f;
    for (int d = dg * 256; d < dg * 256 + 256; ++d) {
        float w = W[(size_t)d * IN_ + col];
        acc1 += w * a1[d];
        acc2 += w * a2[d];
    }
    __shared__ float r1[4][64], r2[4][64];
    r1[dg][t & 63] = acc1;
    r2[dg][t & 63] = acc2;
    __syncthreads();
    if (t < 64) {
        ws[WA1 + blockIdx.x * 64 + t] = r1[0][t] + r1[1][t] + r1[2][t] + r1[3][t];
        ws[WA2 + blockIdx.x * 64 + t] = r2[0][t] + r2[1][t] + r2[2][t] + r2[3][t];
    }
}

// c1 = w_b.a1, c2 = w_b.a2
__global__ void kG(const float* __restrict__ wb, const float* __restrict__ aw,
                   float* __restrict__ ws) {
    int t = threadIdx.x;
    float p1 = 0.f, p2 = 0.f;
    for (int d = t; d < OUT_; d += 256) {
        p1 += wb[d] * aw[d];
        p2 += wb[d] * aw[OUT_ + d];
    }
    __shared__ float r1[256], r2[256];
    r1[t] = p1; r2[t] = p2;
    __syncthreads();
    for (int off = 128; off > 0; off >>= 1) {
        if (t < off) { r1[t] += r1[t + off]; r2[t] += r2[t + off]; }
        __syncthreads();
    }
    if (t == 0) { ws[C12] = r1[0]; ws[C12 + 1] = r2[0]; }
}

// e0[b] = f[b,0,:].wa1  (one wave per b)
__global__ void kP(const float* __restrict__ f, float* __restrict__ ws) {
    int t = threadIdx.x, wave = t >> 6, lane = t & 63;
    int b = blockIdx.x * 4 + wave;
    const float4* f4    = (const float4*)(f + (size_t)b * N_ * IN_);
    const float4* wa1_4 = (const float4*)(ws + WA1);
    float a = 0.f;
    #pragma unroll
    for (int k = 0; k < 4; ++k) {
        float4 v  = f4[k * 64 + lane];
        float4 w1 = wa1_4[k * 64 + lane];
        a += v.x * w1.x + v.y * w1.y + v.z * w1.z + v.w * w1.w;
    }
    a = wave_reduce_sum(a);
    if (lane == 0) ws[E0 + b] = a;
}

// Single feature pass: per row n, s=f.wa2, w=exp(leaky(e0+c+s)),
// accumulate gpart += w*f and zpart += w.   Wave-per-row, reg double-buffer.
__global__ void kMain(const float* __restrict__ f, const float* __restrict__ ab,
                      float* __restrict__ ws) {
    int b = blockIdx.y, chunk = blockIdx.x;
    int t = threadIdx.x, wave = t >> 6, lane = t & 63;
    float cst = ws[E0 + b] + ws[C12] + ws[C12 + 1] + ab[0];

    const float4* wa2_4 = (const float4*)(ws + WA2);
    float4 ra2[4];
    #pragma unroll
    for (int k = 0; k < 4; ++k) ra2[k] = wa2_4[k * 64 + lane];

    const float4* fbase = (const float4*)(f + ((size_t)b * N_ + (size_t)chunk * CHUNK) * IN_);
    float4 acc[4];
    #pragma unroll
    for (int k = 0; k < 4; ++k) acc[k] = make_float4(0.f, 0.f, 0.f, 0.f);
    float z = 0.f;

    float4 v[4], nv[4];
    int r = wave;
    #pragma unroll
    for (int k = 0; k < 4; ++k) v[k] = fbase[(size_t)r * 256 + k * 64 + lane];

    for (int i = 0; i < RPW; ++i) {
        int rn = r + 4;
        if (i + 1 < RPW) {
            #pragma unroll
            for (int k = 0; k < 4; ++k) nv[k] = fbase[(size_t)rn * 256 + k * 64 + lane];
        }
        float dot = 0.f;
        #pragma unroll
        for (int k = 0; k < 4; ++k)
            dot += v[k].x * ra2[k].x + v[k].y * ra2[k].y + v[k].z * ra2[k].z + v[k].w * ra2[k].w;
        dot = wave_reduce_sum(dot);
        float e = dot + cst;
        e = e >= 0.f ? e : ALPHA * e;
        float w = __expf(e);
        z += w;
        #pragma unroll
        for (int k = 0; k < 4; ++k) {
            acc[k].x += w * v[k].x; acc[k].y += w * v[k].y;
            acc[k].z += w * v[k].z; acc[k].w += w * v[k].w;
        }
        if (i + 1 < RPW) {
            #pragma unroll
            for (int k = 0; k < 4; ++k) v[k] = nv[k];
        }
        r = rn;
    }

    __shared__ float4 gbuf[4][256];
    __shared__ float  zbuf[4];
    #pragma unroll
    for (int k = 0; k < 4; ++k) gbuf[wave][k * 64 + lane] = acc[k];
    if (lane == 0) zbuf[wave] = z;
    __syncthreads();
    float4 s0 = gbuf[0][t], s1 = gbuf[1][t], s2 = gbuf[2][t], s3 = gbuf[3][t];
    float4 s = make_float4(s0.x + s1.x + s2.x + s3.x, s0.y + s1.y + s2.y + s3.y,
                           s0.z + s1.z + s2.z + s3.z, s0.w + s1.w + s2.w + s3.w);
    ((float4*)(ws + GPART))[((size_t)b * NCH + chunk) * 256 + t] = s;
    if (t == 0) ws[ZPART + b * NCH + chunk] = zbuf[0] + zbuf[1] + zbuf[2] + zbuf[3];
}

// g[b,:] = (sum_c gpart[b,c,:]) / (sum_c zpart[b,c])
__global__ void kE(float* __restrict__ ws) {
    int b = blockIdx.x, t = threadIdx.x;
    __shared__ float zinv;
    if (t == 0) {
        float zz = 0.f;
        #pragma unroll
        for (int c = 0; c < NCH; ++c) zz += ws[ZPART + b * NCH + c];
        zinv = 1.0f / zz;
    }
    __syncthreads();
    const float4* gp = (const float4*)(ws + GPART);
    float4 acc = make_float4(0.f, 0.f, 0.f, 0.f);
    #pragma unroll
    for (int c = 0; c < NCH; ++c) {
        float4 v = gp[((size_t)b * NCH + c) * 256 + t];
        acc.x += v.x; acc.y += v.y; acc.z += v.z; acc.w += v.w;
    }
    acc.x *= zinv; acc.y *= zinv; acc.z *= zinv; acc.w *= zinv;
    ((float4*)(ws + GV))[b * 256 + t] = acc;
}

// out[b,d] = relu( g[b,:].W[d,:] + w_b[d] + bias_out[d] )
__global__ void kF(const float* __restrict__ W, const float* __restrict__ wb,
                   const float* __restrict__ bias, const float* __restrict__ ws,
                   float* __restrict__ out) {
    int b = blockIdx.x, t = threadIdx.x;
    int dbase = blockIdx.y * 4;
    __shared__ float sg[IN_];
    ((float4*)sg)[t] = ((const float4*)(ws + GV))[b * 256 + t];
    __syncthreads();
    int wave = t >> 6, lane = t & 63;
    int d = dbase + wave;
    const float4* w4 = (const float4*)(W + (size_t)d * IN_);
    float acc = 0.f;
    #pragma unroll
    for (int k = 0; k < 4; ++k) {
        float4 wv = w4[k * 64 + lane];
        int i = (k * 64 + lane) * 4;
        acc += wv.x * sg[i] + wv.y * sg[i + 1] + wv.z * sg[i + 2] + wv.w * sg[i + 3];
    }
    acc = wave_reduce_sum(acc);
    if (lane == 0) {
        float p = acc + wb[d] + bias[d];
        out[(size_t)b * OUT_ + d] = p > 0.f ? p : 0.f;
    }
}

extern "C" void kernel_launch(void* const* d_in, const int* in_sizes, int n_in,
                              void* d_out, int out_size, void* d_ws, size_t ws_size,
                              hipStream_t stream) {
    const float* f    = (const float*)d_in[0];  // (64,2048,1024)
    const float* W    = (const float*)d_in[1];  // (1024,1024)
    const float* wb   = (const float*)d_in[2];  // (1024,)
    const float* aw   = (const float*)d_in[3];  // (2048,)
    const float* ab   = (const float*)d_in[4];  // scalar
    const float* bias = (const float*)d_in[5];  // (1024,)
    float* out = (float*)d_out;                 // (64,1,1024) f32
    float* ws  = (float*)d_ws;

    kA<<<dim3(IN_ / 64), 256, 0, stream>>>(W, aw, ws);
    kG<<<dim3(1), 256, 0, stream>>>(wb, aw, ws);
    kP<<<dim3(B_ / 4), 256, 0, stream>>>(f, ws);
    kMain<<<dim3(NCH, B_), 256, 0, stream>>>(f, ab, ws);
    kE<<<dim3(B_), 256, 0, stream>>>(ws);
    kF<<<dim3(B_, OUT_ / 4), 256, 0, stream>>>(W, wb, bias, ws, out);
}